// Round 10
// baseline (86.828 us; speedup 1.0000x reference)
//
#include <hip/hip_runtime.h>
#include <hip/hip_bf16.h>

typedef __attribute__((ext_vector_type(8))) short short8;
typedef __attribute__((ext_vector_type(4))) float f32x4;

#define NC    91
#define DM    64
#define CIN   128
#define NMOV  4206
#define MR    96
#define HP    68      // hbuf fp32 pitch
#define GP    92      // gram fp32 pitch
#define NT    1024
#define NW    16

// d_ws bf16 weight offsets (in shorts)
#define W_EMBED 0
#define W_IN    8192
#define W_OUT   20480
#define W_FF1   24576
#define W_FF2   32768
#define W_FT    40960
#define W_TOTAL 49152

__constant__ int HEXOFF[NC] = {
  55,66,77,88,99,110,
  45,56,67,78,89,100,111,
  35,46,57,68,79,90,101,112,
  25,36,47,58,69,80,91,102,113,
  15,26,37,48,59,70,81,92,103,114,
  5,16,27,38,49,60,71,82,93,104,115,
  6,17,28,39,50,61,72,83,94,105,
  7,18,29,40,51,62,73,84,95,
  8,19,30,41,52,63,74,85,
  9,20,31,42,53,64,75,
  10,21,32,43,54,65
};

#define SWZ(row, col, PB) ((row)*(PB) + ((((((col)*2)>>4)) ^ ((row)&7)) << 4) + (((col)*2)&15))

__device__ __forceinline__ short f2bf(float f) {
  __hip_bfloat16 h = __float2bfloat16(f);
  return __builtin_bit_cast(short, h);
}
__device__ __forceinline__ float bflo(unsigned u){ return __builtin_bit_cast(float, u << 16); }
__device__ __forceinline__ float bfhi(unsigned u){ return __builtin_bit_cast(float, u & 0xffff0000u); }

__device__ __forceinline__ short8 ldfrag128(const short* buf, int row, int k0) {
  return *(const short8*)((const char*)buf + SWZ(row, k0, 128));
}
__device__ __forceinline__ short8 ldfrag256(const short* buf, int row, int k0) {
  return *(const short8*)((const char*)buf + SWZ(row, k0, 256));
}
__device__ __forceinline__ void stb16_128(short* buf, int row, int col, float v) {
  *(short*)((char*)buf + SWZ(row, col, 128)) = f2bf(v);
}
// B-fragment straight from global bf16 weights (row-major, K elems/row)
__device__ __forceinline__ short8 gfrag(const short* gw, int row, int K, int k0) {
  return *(const short8*)(gw + row*K + k0);
}

// 16-lane-group LayerNorm -> ab16 bf16 (swz PB=128)
__device__ __forceinline__ void ln_group(const float* hbuf, short* ab16,
                                         const float* gw, const float* gb,
                                         int wid, int lane) {
  const int sub = lane >> 4;
  const int l16 = lane & 15;
  const float4 g4 = *(const float4*)&gw[l16*4];
  const float4 b4 = *(const float4*)&gb[l16*4];
  for (int g = wid; g < 23; g += NW) {
    int i = g*4 + sub;
    if (i < NC) {
      float4 v = *(const float4*)&hbuf[i*HP + l16*4];
      float s  = (v.x + v.y) + (v.z + v.w);
      float sq = fmaf(v.x,v.x, fmaf(v.y,v.y, fmaf(v.z,v.z, v.w*v.w)));
      #pragma unroll
      for (int off = 1; off < 16; off <<= 1) {
        s  += __shfl_xor(s, off, 64);
        sq += __shfl_xor(sq, off, 64);
      }
      float m  = s * (1.0f/64.0f);
      float vr = sq * (1.0f/64.0f) - m*m;
      float rs = rsqrtf(vr + 1e-5f);
      short4 o;
      o.x = f2bf((v.x - m)*rs*g4.x + b4.x);
      o.y = f2bf((v.y - m)*rs*g4.y + b4.y);
      o.z = f2bf((v.z - m)*rs*g4.z + b4.z);
      o.w = f2bf((v.w - m)*rs*g4.w + b4.w);
      *(short4*)((char*)ab16 + i*128 + (((l16>>1) ^ (i&7))<<4) + (l16&1)*8) = o;
    }
  }
}

__global__ __launch_bounds__(256)
void prep_w(const float* __restrict__ embed_w, const float* __restrict__ in_w,
            const float* __restrict__ out_w, const float* __restrict__ ff1_w,
            const float* __restrict__ ff2_w, const float* __restrict__ from_w,
            const float* __restrict__ to_w, short* __restrict__ ws)
{
  int i = blockIdx.x*256 + threadIdx.x;
  if (i >= W_TOTAL) return;
  float v;
  if      (i < 8192)  v = embed_w[i];
  else if (i < 20480) v = in_w[i - 8192];
  else if (i < 24576) v = out_w[i - 20480];
  else if (i < 32768) v = ff1_w[i - 24576];
  else if (i < 40960) v = ff2_w[i - 32768];
  else if (i < 45056) v = from_w[i - 40960];
  else                v = to_w[i - 45056];
  ws[i] = f2bf(v);
}

__global__ __launch_bounds__(1024, 8)
void policy_fused(
    const float* __restrict__ x,
    const float* __restrict__ embed_b, const float* __restrict__ pos,
    const float* __restrict__ in_b,  const float* __restrict__ out_b,
    const float* __restrict__ ln1_g, const float* __restrict__ ln1_b,
    const float* __restrict__ ln2_g, const float* __restrict__ ln2_b,
    const float* __restrict__ ff1_b, const float* __restrict__ ff2_b,
    const float* __restrict__ from_b, const float* __restrict__ to_b,
    const float* __restrict__ move_bias,
    const int* __restrict__ move_from, const int* __restrict__ move_to,
    const short* __restrict__ ws,
    float* __restrict__ out)
{
  __shared__ float Abuf[8736];       // 34944B: feats / qkv bf16 / f1 / G
  __shared__ float Bbuf[MR*HP];      // 26112B: hbuf ; F,T alias after P8
  __shared__ short ab16[MR*64];      // 12288B

  const int tid  = threadIdx.x;
  const int lane = tid & 63;
  const int wid  = tid >> 6;
  const int l15  = lane & 15;
  const int kfr  = (lane >> 4) * 8;
  const int mfr  = (lane >> 4) * 4;
  const int b    = blockIdx.x;
  const float* xb = x + (size_t)b * (CIN*121);

  float* hbuf   = Bbuf;
  short* featsb = (short*)Abuf;                  // [96][128] bf16 swz PB=256
  short* qb = (short*)Abuf;                      // [4][91][16] bf16 (row 32B)
  short* kb = qb + 4*NC*16;
  short* vb = kb + 4*NC*16;
  short* f1 = (short*)Abuf;                      // [96][128] bf16 swz PB=256
  float* G  = Abuf;                              // [91][92] fp32

  // ---- P0: hex-gather feats -> bf16 ----
  for (int e = tid; e < 16*NC; e += NT) {
    int c0 = e / NC, i = e - c0*NC;
    float v[8];
    #pragma unroll
    for (int u = 0; u < 8; ++u) v[u] = xb[(c0*8 + u)*121 + HEXOFF[i]];
    short8 s8;
    #pragma unroll
    for (int u = 0; u < 8; ++u) s8[u] = f2bf(v[u]);
    *(short8*)((char*)featsb + i*256 + ((c0 ^ (i&7)) << 4)) = s8;
  }
  if (tid < 320) ((unsigned*)featsb)[5824 + tid] = 0;   // zero feats rows 91..95
  __syncthreads();

  // ---- P1: embed MFMA (K=128), B from ws ----
  for (int t = wid; t < 24; t += NW) {
    int mt = t >> 2, nt = t & 3;
    int ar = mt*16 + l15, br = nt*16 + l15;
    f32x4 acc = {0.f,0.f,0.f,0.f};
    #pragma unroll
    for (int kk = 0; kk < 4; ++kk) {
      short8 a = ldfrag256(featsb, ar, kk*32 + kfr);
      short8 w = gfrag(ws + W_EMBED, br, 128, kk*32 + kfr);
      acc = __builtin_amdgcn_mfma_f32_16x16x32_bf16(a, w, acc, 0, 0, 0);
    }
    int col = nt*16 + l15;
    float eb = embed_b[col];
    #pragma unroll
    for (int i2 = 0; i2 < 4; ++i2) {
      int m = mt*16 + mfr + i2;
      float p = (m < NC) ? pos[m*DM + col] : 0.f;
      hbuf[m*HP + col] = acc[i2] + eb + p;
    }
  }
  __syncthreads();

  // ---- P2: zero ab16 tail + LN1 -> ab16 ----
  if (tid < 160) ((unsigned*)ab16)[2912 + tid] = 0;
  ln_group(hbuf, ab16, ln1_g, ln1_b, wid, lane);
  __syncthreads();

  // ---- P3: qkv MFMA (N=192,K=64) -> q/k/v bf16 head layout ----
  for (int t = wid; t < 72; t += NW) {
    int mt = t / 12, nt = t - mt*12;
    int ar = mt*16 + l15, br = nt*16 + l15;
    f32x4 acc = {0.f,0.f,0.f,0.f};
    #pragma unroll
    for (int kk = 0; kk < 2; ++kk) {
      short8 a = ldfrag128(ab16, ar, kk*32 + kfr);
      short8 w = gfrag(ws + W_IN, br, 64, kk*32 + kfr);
      acc = __builtin_amdgcn_mfma_f32_16x16x32_bf16(a, w, acc, 0, 0, 0);
    }
    int col = nt*16 + l15;
    float bia = in_b[col];
    int hl = (col & 63) >> 4;
    int d  = col & 15;
    short* dst = (col < 64) ? qb : ((col < 128) ? kb : vb);
    #pragma unroll
    for (int i2 = 0; i2 < 4; ++i2) {
      int m = mt*16 + mfr + i2;
      if (m < NC) dst[(hl*NC + m)*16 + d] = f2bf(acc[i2] + bia);
    }
  }
  __syncthreads();

  // ---- P4: attention, 2 threads per (h,i), bf16 k/v via shift-cvt ----
  {
    const int q2   = tid >> 1;
    const int half = tid & 1;
    if (q2 < 4*NC) {
      const int h = q2 / NC;
      const int i = q2 - h*NC;
      const float CS = 0.25f * 1.4426950408889634f;
      const unsigned* qp = (const unsigned*)(qb + (h*NC + i)*16);
      uint4 qv0 = *(const uint4*)qp, qv1 = *(const uint4*)(qp + 4);
      float q0=bflo(qv0.x)*CS, q1=bfhi(qv0.x)*CS, q2f=bflo(qv0.y)*CS, q3=bfhi(qv0.y)*CS,
            q4=bflo(qv0.z)*CS, q5=bfhi(qv0.z)*CS, q6=bflo(qv0.w)*CS, q7=bfhi(qv0.w)*CS,
            q8=bflo(qv1.x)*CS, q9=bfhi(qv1.x)*CS, qA=bflo(qv1.y)*CS, qB=bfhi(qv1.y)*CS,
            qC=bflo(qv1.z)*CS, qD=bfhi(qv1.z)*CS, qE=bflo(qv1.w)*CS, qF=bfhi(qv1.w)*CS;
      const unsigned* kp = (const unsigned*)(kb + h*NC*16);
      const unsigned* vp = (const unsigned*)(vb + h*NC*16);
      float4 oa = {0,0,0,0}, obv = {0,0,0,0}, ocv = {0,0,0,0}, odv = {0,0,0,0};
      float lrun = 0.0f;
      const int j0 = half ? 46 : 0;
      const int j1 = half ? NC : 46;
      for (int j = j0; j < j1; ++j) {
        uint4 k0v = *(const uint4*)(kp + j*8);
        uint4 k1v = *(const uint4*)(kp + j*8 + 4);
        float t0 = fmaf(q1, bfhi(k0v.x), q0*bflo(k0v.x));
        t0 = fmaf(q3, bfhi(k0v.y), fmaf(q2f, bflo(k0v.y), t0));
        float t1 = fmaf(q5, bfhi(k0v.z), q4*bflo(k0v.z));
        t1 = fmaf(q7, bfhi(k0v.w), fmaf(q6, bflo(k0v.w), t1));
        float t2 = fmaf(q9, bfhi(k1v.x), q8*bflo(k1v.x));
        t2 = fmaf(qB, bfhi(k1v.y), fmaf(qA, bflo(k1v.y), t2));
        float t3 = fmaf(qD, bfhi(k1v.z), qC*bflo(k1v.z));
        t3 = fmaf(qF, bfhi(k1v.w), fmaf(qE, bflo(k1v.w), t3));
        float pw = exp2f((t0+t1)+(t2+t3));
        lrun += pw;
        uint4 v0v = *(const uint4*)(vp + j*8);
        uint4 v1v = *(const uint4*)(vp + j*8 + 4);
        oa.x  = fmaf(pw, bflo(v0v.x), oa.x);  oa.y  = fmaf(pw, bfhi(v0v.x), oa.y);
        oa.z  = fmaf(pw, bflo(v0v.y), oa.z);  oa.w  = fmaf(pw, bfhi(v0v.y), oa.w);
        obv.x = fmaf(pw, bflo(v0v.z), obv.x); obv.y = fmaf(pw, bfhi(v0v.z), obv.y);
        obv.z = fmaf(pw, bflo(v0v.w), obv.z); obv.w = fmaf(pw, bfhi(v0v.w), obv.w);
        ocv.x = fmaf(pw, bflo(v1v.x), ocv.x); ocv.y = fmaf(pw, bfhi(v1v.x), ocv.y);
        ocv.z = fmaf(pw, bflo(v1v.y), ocv.z); ocv.w = fmaf(pw, bfhi(v1v.y), ocv.w);
        odv.x = fmaf(pw, bflo(v1v.z), odv.x); odv.y = fmaf(pw, bfhi(v1v.z), odv.y);
        odv.z = fmaf(pw, bflo(v1v.w), odv.z); odv.w = fmaf(pw, bfhi(v1v.w), odv.w);
      }
      lrun += __shfl_xor(lrun, 1, 64);
      #define MRG(c) c += __shfl_xor(c, 1, 64)
      MRG(oa.x); MRG(oa.y); MRG(oa.z); MRG(oa.w);
      MRG(obv.x); MRG(obv.y); MRG(obv.z); MRG(obv.w);
      MRG(ocv.x); MRG(ocv.y); MRG(ocv.z); MRG(ocv.w);
      MRG(odv.x); MRG(odv.y); MRG(odv.z); MRG(odv.w);
      #undef MRG
      float inv = 1.0f / lrun;
      float4 w0 = half ? ocv : oa;
      float4 w1 = half ? odv : obv;
      short8 ow;
      ow[0]=f2bf(w0.x*inv); ow[1]=f2bf(w0.y*inv); ow[2]=f2bf(w0.z*inv); ow[3]=f2bf(w0.w*inv);
      ow[4]=f2bf(w1.x*inv); ow[5]=f2bf(w1.y*inv); ow[6]=f2bf(w1.z*inv); ow[7]=f2bf(w1.w*inv);
      *(short8*)((char*)ab16 + SWZ(i, h*16 + half*8, 128)) = ow;
    }
  }
  __syncthreads();

  // ---- P5: out-proj MFMA: hbuf += o @ out_w^T + out_b ----
  for (int t = wid; t < 24; t += NW) {
    int mt = t >> 2, nt = t & 3;
    int ar = mt*16 + l15, br = nt*16 + l15;
    f32x4 acc = {0.f,0.f,0.f,0.f};
    #pragma unroll
    for (int kk = 0; kk < 2; ++kk) {
      short8 a = ldfrag128(ab16, ar, kk*32 + kfr);
      short8 w = gfrag(ws + W_OUT, br, 64, kk*32 + kfr);
      acc = __builtin_amdgcn_mfma_f32_16x16x32_bf16(a, w, acc, 0, 0, 0);
    }
    int col = nt*16 + l15;
    float ob = out_b[col];
    #pragma unroll
    for (int i2 = 0; i2 < 4; ++i2) {
      int m = mt*16 + mfr + i2;
      hbuf[m*HP + col] += acc[i2] + ob;
    }
  }
  __syncthreads();

  // ---- P6: LN2 -> ab16 ----
  ln_group(hbuf, ab16, ln2_g, ln2_b, wid, lane);
  __syncthreads();

  // ---- P7: ff1 MFMA (N=128,K=64) -> f1 bf16 ----
  for (int t = wid; t < 48; t += NW) {
    int mt = t >> 3, nt = t & 7;
    int ar = mt*16 + l15, br = nt*16 + l15;
    f32x4 acc = {0.f,0.f,0.f,0.f};
    #pragma unroll
    for (int kk = 0; kk < 2; ++kk) {
      short8 a = ldfrag128(ab16, ar, kk*32 + kfr);
      short8 w = gfrag(ws + W_FF1, br, 64, kk*32 + kfr);
      acc = __builtin_amdgcn_mfma_f32_16x16x32_bf16(a, w, acc, 0, 0, 0);
    }
    int col = nt*16 + l15;
    float bia = ff1_b[col];
    #pragma unroll
    for (int i2 = 0; i2 < 4; ++i2) {
      int m = mt*16 + mfr + i2;
      *(short*)((char*)f1 + SWZ(m, col, 256)) = f2bf(fmaxf(acc[i2] + bia, 0.f));
    }
  }
  __syncthreads();

  // ---- P8: ff2 MFMA (K=128): ab16 = bf16(hbuf + f1@W^T + b) ----
  for (int t = wid; t < 24; t += NW) {
    int mt = t >> 2, nt = t & 3;
    int ar = mt*16 + l15, br = nt*16 + l15;
    f32x4 acc = {0.f,0.f,0.f,0.f};
    #pragma unroll
    for (int kk = 0; kk < 4; ++kk) {
      short8 a = ldfrag256(f1, ar, kk*32 + kfr);
      short8 w = gfrag(ws + W_FF2, br, 128, kk*32 + kfr);
      acc = __builtin_amdgcn_mfma_f32_16x16x32_bf16(a, w, acc, 0, 0, 0);
    }
    int col = nt*16 + l15;
    float bia = ff2_b[col];
    #pragma unroll
    for (int i2 = 0; i2 < 4; ++i2) {
      int m = mt*16 + mfr + i2;
      stb16_128(ab16, m, col, hbuf[m*HP + col] + acc[i2] + bia);
    }
  }
  __syncthreads();

  // ---- P9: from/to MFMA (N=128,K=64) -> F,T bf16 (alias hbuf region) ----
  short* Fb = (short*)Bbuf;
  short* Tb = (short*)Bbuf + 6144;
  for (int t = wid; t < 48; t += NW) {
    int mt = t >> 3, nt = t & 7;
    int ar = mt*16 + l15, br = nt*16 + l15;
    f32x4 acc = {0.f,0.f,0.f,0.f};
    #pragma unroll
    for (int kk = 0; kk < 2; ++kk) {
      short8 a = ldfrag128(ab16, ar, kk*32 + kfr);
      short8 w = gfrag(ws + W_FT, br, 64, kk*32 + kfr);
      acc = __builtin_amdgcn_mfma_f32_16x16x32_bf16(a, w, acc, 0, 0, 0);
    }
    int col = nt*16 + l15;
    if (nt < 4) {
      float bia = from_b[col];
      #pragma unroll
      for (int i2 = 0; i2 < 4; ++i2)
        stb16_128(Fb, mt*16 + mfr + i2, col, acc[i2] + bia);
    } else {
      int c2 = col - 64;
      float bia = to_b[c2];
      #pragma unroll
      for (int i2 = 0; i2 < 4; ++i2)
        stb16_128(Tb, mt*16 + mfr + i2, c2, acc[i2] + bia);
    }
  }
  __syncthreads();

  // ---- P10: gram MFMA: G = F @ T^T -> Abuf (pitch 92; clamp col to pitch!) ----
  for (int t = wid; t < 36; t += NW) {
    int mt = t / 6, nt = t - mt*6;
    int ar = mt*16 + l15, br = nt*16 + l15;
    f32x4 acc = {0.f,0.f,0.f,0.f};
    #pragma unroll
    for (int kk = 0; kk < 2; ++kk) {
      short8 a = ldfrag128(Fb, ar, kk*32 + kfr);
      short8 w = ldfrag128(Tb, br, kk*32 + kfr);
      acc = __builtin_amdgcn_mfma_f32_16x16x32_bf16(a, w, acc, 0, 0, 0);
    }
    int col = nt*16 + l15;
    if (col < GP) {                       // FIX: cols 92..95 would stomp next row
      #pragma unroll
      for (int i2 = 0; i2 < 4; ++i2) {
        int m = mt*16 + mfr + i2;
        if (m < NC) G[m*GP + col] = acc[i2];
      }
    }
  }
  __syncthreads();

  // ---- P11: logits gather ----
  {
    float* ob = out + (size_t)b * NMOV;
    for (int m = tid; m < NMOV; m += NT) {
      ob[m] = G[move_from[m]*GP + move_to[m]] + move_bias[m];
    }
  }
}

extern "C" void kernel_launch(void* const* d_in, const int* in_sizes, int n_in,
                              void* d_out, int out_size, void* d_ws, size_t ws_size,
                              hipStream_t stream) {
  const float* x        = (const float*)d_in[0];
  const float* embed_w  = (const float*)d_in[1];
  const float* embed_b  = (const float*)d_in[2];
  const float* pos      = (const float*)d_in[3];
  const float* in_w     = (const float*)d_in[4];
  const float* in_b     = (const float*)d_in[5];
  const float* out_w    = (const float*)d_in[6];
  const float* out_b    = (const float*)d_in[7];
  const float* ln1_g    = (const float*)d_in[8];
  const float* ln1_b    = (const float*)d_in[9];
  const float* ln2_g    = (const float*)d_in[10];
  const float* ln2_b    = (const float*)d_in[11];
  const float* ff1_w    = (const float*)d_in[12];
  const float* ff1_b    = (const float*)d_in[13];
  const float* ff2_w    = (const float*)d_in[14];
  const float* ff2_b    = (const float*)d_in[15];
  const float* from_w   = (const float*)d_in[16];
  const float* from_b   = (const float*)d_in[17];
  const float* to_w     = (const float*)d_in[18];
  const float* to_b     = (const float*)d_in[19];
  const float* move_bias= (const float*)d_in[20];
  const int*   move_from= (const int*)d_in[21];
  const int*   move_to  = (const int*)d_in[22];

  short* wsb = (short*)d_ws;
  prep_w<<<dim3((W_TOTAL + 255)/256), dim3(256), 0, stream>>>(
      embed_w, in_w, out_w, ff1_w, ff2_w, from_w, to_w, wsb);

  int B = in_sizes[0] / (CIN * 121);
  policy_fused<<<dim3(B), dim3(NT), 0, stream>>>(
      x, embed_b, pos, in_b, out_b,
      ln1_g, ln1_b, ln2_g, ln2_b, ff1_b, ff2_b,
      from_b, to_b, move_bias, move_from, move_to,
      (const short*)wsb, (float*)d_out);
}